// Round 4
// baseline (809.001 us; speedup 1.0000x reference)
//
#include <hip/hip_runtime.h>
#include <hip/hip_bf16.h>

#define DD 1024
#define HD 512          // d-half processed per LDS stage
#define RR 16
#define MM 512
#define KK 8
#define BB 8
#define RB 32           // rows per block (8 per wave)
#define SCALE_F 0.0625f
#define LDP (HD + 4)    // padded LDS row pitch (kills staging write conflicts)

// reduce-scatter fold chain; after <32,1><16,2><8,4><4,8><2,16> + xor32 add,
// lane l holds the 64-lane total of value j = l&31  (verified in rounds 1-2)
template <int LEN, int XOR>
__device__ __forceinline__ void fold(float (&v)[32], int lane) {
    const bool hi = (lane & XOR) != 0;
#pragma unroll
    for (int i = 0; i < LEN / 2; ++i) {
        const float keep = hi ? v[2 * i + 1] : v[2 * i];
        const float send = hi ? v[2 * i] : v[2 * i + 1];
        v[i] = keep + __shfl_xor(send, XOR, 64);
    }
}

__global__ __launch_bounds__(256, 4)
void lora_fused(const float* __restrict__ z, const float* __restrict__ A_all,
                const float* __restrict__ B_all, const int* __restrict__ eidx,
                float* __restrict__ out)
{
    __shared__ float Sh[RR][LDP];   // 33 KB: holds A^T half, then B half
    __shared__ float dn[RB][RR];    // 2 KB: down-projection results

    const int mc = blockIdx.x, b = blockIdx.y, k = blockIdx.z;
    const int e = eidx[k];
    const int tid  = threadIdx.x;
    const int wave = tid >> 6, lane = tid & 63;

    const size_t rowbase = ((size_t)b * KK + k) * MM + (size_t)mc * RB;
    const int wrow = wave * 8;                       // block-local first row of wave

    const float* __restrict__ Ae = A_all + (size_t)e * (DD * RR);
    const float* __restrict__ Be = B_all + (size_t)e * (RR * DD);

    // =================== DOWN: dn[row][r] = sum_d z[row][d] * A[d][r] ===================
#pragma unroll 1
    for (int h = 0; h < 2; ++h) {
        // stage A^T half: Sh[r][d-h*HD] = A[d][r]
        for (int idx = tid; idx < HD * RR / 4; idx += 256) {
            const int f = h * (HD * RR) + idx * 4;           // flat into A[d][r]
            const float4 v4 = *reinterpret_cast<const float4*>(Ae + f);
            const int d = (f >> 4) - h * HD;
            const int r = f & 15;
            Sh[r + 0][d] = v4.x; Sh[r + 1][d] = v4.y;
            Sh[r + 2][d] = v4.z; Sh[r + 3][d] = v4.w;
        }
        __syncthreads();

        const float* zl = z + (rowbase + wrow) * DD + h * HD + lane * 4;
        float4 bufA[2][2], bufB[2][2];   // 2-row tiles, 2 float4 per row (16 regs each)

        auto ldt = [&](float4 (&bf)[2][2], int t0) {
#pragma unroll
            for (int t = 0; t < 2; ++t)
#pragma unroll
                for (int s = 0; s < 2; ++s)
                    bf[t][s] = *reinterpret_cast<const float4*>(
                        zl + (size_t)(t0 + t) * DD + s * 256);
        };
        auto cmp = [&](const float4 (&bf)[2][2], int t0) {
            float v[32];
#pragma unroll
            for (int i = 0; i < 32; ++i) v[i] = 0.f;
#pragma unroll
            for (int s = 0; s < 2; ++s) {
                const int dbase = s * 256 + lane * 4;
#pragma unroll
                for (int r = 0; r < RR; ++r) {
                    const float4 a = *reinterpret_cast<const float4*>(&Sh[r][dbase]);
#pragma unroll
                    for (int t = 0; t < 2; ++t) {
                        float acc = v[t * 16 + r];
                        acc = fmaf(bf[t][s].x, a.x, acc);
                        acc = fmaf(bf[t][s].y, a.y, acc);
                        acc = fmaf(bf[t][s].z, a.z, acc);
                        acc = fmaf(bf[t][s].w, a.w, acc);
                        v[t * 16 + r] = acc;
                    }
                }
            }
            fold<32, 1>(v, lane); fold<16, 2>(v, lane); fold<8, 4>(v, lane);
            fold<4, 8>(v, lane);  fold<2, 16>(v, lane);
            const float tot = v[0] + __shfl_xor(v[0], 32, 64);
            if (lane < 32) {                                  // j = t*16+r = lane&31
                float* p = &dn[wrow + t0 + (lane >> 4)][lane & 15];
                if (h == 0) *p = tot; else *p += tot;
            }
        };

        // 4 tiles (rows +0,+2,+4,+6), software ping-pong
        ldt(bufA, 0);
#pragma unroll 1
        for (int ip = 0; ip < 2; ++ip) {
            ldt(bufB, 4 * ip + 2);
            cmp(bufA, 4 * ip);
            if (ip == 0) ldt(bufA, 4);
            cmp(bufB, 4 * ip + 2);
        }
        __syncthreads();
    }

    // =================== UP: out[row][d] = SCALE * sum_r dn[row][r] * B[r][d] ===================
#pragma unroll 1
    for (int h = 0; h < 2; ++h) {
        // stage B half: Sh[r][doff] = B[r][h*HD + doff]
        for (int idx = tid; idx < HD * RR / 4; idx += 256) {
            const int r = idx >> 7;                 // 128 float4 per row-half
            const int doff = (idx & 127) * 4;
            const float4 v4 = *reinterpret_cast<const float4*>(Be + r * DD + h * HD + doff);
            *reinterpret_cast<float4*>(&Sh[r][doff]) = v4;
        }
        __syncthreads();

        float* ol = out + (rowbase + wrow) * DD + h * HD + lane * 4;

#pragma unroll 1
        for (int i = 0; i < 4; ++i) {
            const int t0 = 2 * i;
            float c0[16], c1[16];                   // coefficients via LDS broadcast
#pragma unroll
            for (int q = 0; q < 4; ++q) {
                const float4 cv0 = *reinterpret_cast<const float4*>(&dn[wrow + t0 + 0][4 * q]);
                const float4 cv1 = *reinterpret_cast<const float4*>(&dn[wrow + t0 + 1][4 * q]);
                c0[4 * q + 0] = cv0.x; c0[4 * q + 1] = cv0.y; c0[4 * q + 2] = cv0.z; c0[4 * q + 3] = cv0.w;
                c1[4 * q + 0] = cv1.x; c1[4 * q + 1] = cv1.y; c1[4 * q + 2] = cv1.z; c1[4 * q + 3] = cv1.w;
            }
#pragma unroll
            for (int s = 0; s < 2; ++s) {
                const int dbase = s * 256 + lane * 4;
                float4 o0 = make_float4(0.f, 0.f, 0.f, 0.f);
                float4 o1 = make_float4(0.f, 0.f, 0.f, 0.f);
#pragma unroll
                for (int r = 0; r < RR; ++r) {
                    const float4 bv = *reinterpret_cast<const float4*>(&Sh[r][dbase]);
                    o0.x = fmaf(c0[r], bv.x, o0.x); o0.y = fmaf(c0[r], bv.y, o0.y);
                    o0.z = fmaf(c0[r], bv.z, o0.z); o0.w = fmaf(c0[r], bv.w, o0.w);
                    o1.x = fmaf(c1[r], bv.x, o1.x); o1.y = fmaf(c1[r], bv.y, o1.y);
                    o1.z = fmaf(c1[r], bv.z, o1.z); o1.w = fmaf(c1[r], bv.w, o1.w);
                }
                float4 r0, r1;
                r0.x = o0.x * SCALE_F; r0.y = o0.y * SCALE_F; r0.z = o0.z * SCALE_F; r0.w = o0.w * SCALE_F;
                r1.x = o1.x * SCALE_F; r1.y = o1.y * SCALE_F; r1.z = o1.z * SCALE_F; r1.w = o1.w * SCALE_F;
                *reinterpret_cast<float4*>(ol + (size_t)(t0 + 0) * DD + s * 256) = r0;
                *reinterpret_cast<float4*>(ol + (size_t)(t0 + 1) * DD + s * 256) = r1;
            }
        }
        __syncthreads();
    }
}

extern "C" void kernel_launch(void* const* d_in, const int* in_sizes, int n_in,
                              void* d_out, int out_size, void* d_ws, size_t ws_size,
                              hipStream_t stream) {
    const float* z     = (const float*)d_in[0];
    const float* A_all = (const float*)d_in[1];
    const float* B_all = (const float*)d_in[2];
    const int*   eidx  = (const int*)d_in[3];
    float* out = (float*)d_out;

    dim3 grid(MM / RB, BB, KK);    // (16, 8, 8) = 1024 blocks, 4/CU, 16 waves/CU
    dim3 block(256);

    lora_fused<<<grid, block, 0, stream>>>(z, A_all, B_all, eidx, out);
}